// Round 6
// baseline (1320.715 us; speedup 1.0000x reference)
//
#include <hip/hip_runtime.h>
#include <hip/hip_bf16.h>
#include <math.h>

#define NH   8
#define NSEQ 4096
#define NB   2
#define HID  256
#define VD   32
#define RANK 409   // 0-indexed; percentile pos = 0.1*(4096-1) = 409.5 -> lerp(s[409],s[410],0.5)
#define NBIN 256
#define CAP  512   // chunked select buffer (M ~ 410 for this data -> 1 chunk)
#define CCAP 1024  // max candidates handled by O(c^2) rank path
#define ROWS 16    // rows per persistent block; grid = NH*NSEQ/ROWS = 2048 = 8/CU

typedef float floatx4 __attribute__((ext_vector_type(4)));

// exclusive scan over 256 per-thread counts; returns base; total via ref
__device__ __forceinline__ unsigned block_scan_excl(unsigned c, int tid,
                                                    volatile unsigned* s4,
                                                    unsigned& total) {
  const int lane = tid & 63, w = tid >> 6;
  unsigned incl = c;
#pragma unroll
  for (int d = 1; d < 64; d <<= 1) {
    unsigned o = __shfl_up(incl, d, 64);
    if (lane >= d) incl += o;
  }
  __syncthreads();
  if (lane == 63) s4[w] = incl;
  __syncthreads();
  unsigned base = 0;
#pragma unroll
  for (int i = 0; i < 4; i++)
    if (i < w) base += s4[i];
  total = s4[0] + s4[1] + s4[2] + s4[3];
  return base + incl - c;
}

// ---------------- kernel A: value[h][n][b*32+k] = x @ weight; + scales ------

__global__ __launch_bounds__(256) void value_kernel(
    const float* __restrict__ x, const float* __restrict__ w,
    const float* __restrict__ r, float* __restrict__ value,
    float* __restrict__ scales) {
  const int tid = threadIdx.x;

  if (blockIdx.x == 0 && tid < NH) {
    double rv = (double)r[tid];
    const float c0 = (float)(0.25 * 3.141592653589793 * (1.0 - 1e-07));
    float s1 = (float)sin(rv);
    float t = c0 * (1.0f + s1);
    scales[tid] = (float)tan((double)t);
  }

  const int n0 = blockIdx.x * 8;
  __shared__ float sx[NB][8][HID];
#pragma unroll
  for (int i = 0; i < 16; i++) {
    int idx = i * 256 + tid;
    int b = idx >> 11;
    int rem = idx & 2047;
    int nn = rem >> 8;
    int j = rem & 255;
    sx[b][nn][j] = x[((size_t)b * NSEQ + n0 + nn) * HID + j];
  }
  __syncthreads();

  const int h = tid >> 5, k = tid & 31;
  float acc[NB][8];
#pragma unroll
  for (int b = 0; b < NB; b++)
#pragma unroll
    for (int nn = 0; nn < 8; nn++) acc[b][nn] = 0.f;

  const float* wp = w + (size_t)h * HID * VD + k;
  for (int j4 = 0; j4 < HID; j4 += 4) {
    float wv0 = wp[(size_t)(j4 + 0) * VD];
    float wv1 = wp[(size_t)(j4 + 1) * VD];
    float wv2 = wp[(size_t)(j4 + 2) * VD];
    float wv3 = wp[(size_t)(j4 + 3) * VD];
#pragma unroll
    for (int b = 0; b < NB; b++) {
#pragma unroll
      for (int nn = 0; nn < 8; nn++) {
        const float4 xv = *reinterpret_cast<const float4*>(&sx[b][nn][j4]);
        float a = acc[b][nn];
        a = fmaf(xv.x, wv0, a);
        a = fmaf(xv.y, wv1, a);
        a = fmaf(xv.z, wv2, a);
        a = fmaf(xv.w, wv3, a);
        acc[b][nn] = a;
      }
    }
  }
#pragma unroll
  for (int b = 0; b < NB; b++)
#pragma unroll
    for (int nn = 0; nn < 8; nn++)
      value[((size_t)h * NSEQ + n0 + nn) * (NB * VD) + b * VD + k] = acc[b][nn];
}

// ---------------- kernel B: persistent; per row: percentile->softmax->gather

__global__ __launch_bounds__(256, 8) void attn_kernel(
    const float* __restrict__ m_dist, const float* __restrict__ value,
    const float* __restrict__ scales, float* __restrict__ out) {
  const int tid = threadIdx.x;
  const int lane = tid & 63;
  const int wv = tid >> 6;
  // 2048 blocks; blk&7 presumed XCD id -> one head per XCD (value slice L2-resident)
  const int blk = blockIdx.x;
  const int h = blk & 7;
  const int qbase = (blk >> 3) * ROWS;

  __shared__ unsigned s_hist[NBIN];       // 1 KB
  __shared__ float4 s_wi4[(CAP + 64) / 2];  // 4.5 KB select buffer (16B-aligned)
  __shared__ float s_out[16][64];         // 4 KB: [wave*4+slot][col]
  __shared__ unsigned s_scanA[4];
  __shared__ unsigned s_scanB[4];
  __shared__ float s_psum[4];
  __shared__ float s_redf[16];            // cmin[4], cmax[4], mgt[4], lmin[4]
  __shared__ unsigned s_redc[4];
  __shared__ unsigned s_bcu[4];
  __shared__ float s_bcf[2];
  float2* s_wi = reinterpret_cast<float2*>(s_wi4);

  // hoisted per-head constants
  const float scale = scales[h];
  const float binscale = (float)NBIN / scale;  // inf/0-safe: cvt NaN->0, clamped
  const char* vpb = (const char*)(value + (size_t)h * (NSEQ * NB * VD)) + (lane & 15) * 16;
  const int slot2 = ((wv * 4) + (lane >> 4)) * 2;  // gather: entry pair index within 64

  for (int rit = 0; rit < ROWS; ++rit) {
    const int q = qbase + rit;
    const size_t rowbase = ((size_t)(h * NSEQ + q)) * NSEQ;

    // ---- load row (thread owns n = 16*tid + i), scale, local min ----
    float v[16];
    {
      const floatx4* row4 = reinterpret_cast<const floatx4*>(m_dist + rowbase) + (size_t)tid * 4;
#pragma unroll
      for (int a = 0; a < 4; a++) {
        floatx4 t4 = __builtin_nontemporal_load(&row4[a]);
        v[4 * a + 0] = t4.x * scale;
        v[4 * a + 1] = t4.y * scale;
        v[4 * a + 2] = t4.z * scale;
        v[4 * a + 3] = t4.w * scale;
      }
    }
    float lmin = v[0];
#pragma unroll
    for (int i = 1; i < 16; i++) lmin = fminf(lmin, v[i]);

    s_hist[tid] = 0u;  // NBIN == 256
    __syncthreads();

    // ---- level-0 histogram; bins kept in registers (computed ONCE) ----
    int bins[16];
#pragma unroll
    for (int i = 0; i < 16; i++) {
      int b = (int)(v[i] * binscale);
      b = b < 0 ? 0 : (b > NBIN - 1 ? NBIN - 1 : b);
      bins[i] = b;
      atomicAdd(&s_hist[b], 1u);
    }
    __syncthreads();

    // ---- locate bin containing rank RANK (1 bin per thread) ----
    {
      unsigned c1 = s_hist[tid];
      unsigned tot;
      unsigned base = block_scan_excl(c1, tid, s_scanA, tot);
      if (base <= (unsigned)RANK && (unsigned)RANK < base + c1) {
        s_bcu[0] = (unsigned)tid;
        s_bcu[1] = (unsigned)RANK - base;
      }
      if (tid == 0) s_bcu[2] = 0u;
    }
    __syncthreads();
    unsigned tb = s_bcu[0];
    unsigned rr = s_bcu[1];

    // ---- mask of candidates + running min-above-bin ----
    unsigned mask = 0;
    float mgt_run = INFINITY;
#pragma unroll
    for (int i = 0; i < 16; i++) {
      if ((unsigned)bins[i] == tb) mask |= (1u << i);
      else if ((unsigned)bins[i] > tb) mgt_run = fminf(mgt_run, v[i]);
    }

    float curlo = 0.f, curbs = binscale;  // cold-path refine state
    float v409, v410, minT;

    // ---- multi-level rank refinement (hot path exits at level 0) ----
    for (int level = 0;; level++) {
      float cmin = INFINITY, cmax = -INFINITY;
      int c = 0;
#pragma unroll
      for (int i = 0; i < 16; i++)
        if (mask & (1u << i)) {
          cmin = fminf(cmin, v[i]);
          cmax = fmaxf(cmax, v[i]);
          c++;
        }
      float mg = mgt_run, lm = lmin;
#pragma unroll
      for (int d = 32; d; d >>= 1) {
        cmin = fminf(cmin, __shfl_down(cmin, d, 64));
        cmax = fmaxf(cmax, __shfl_down(cmax, d, 64));
        mg = fminf(mg, __shfl_down(mg, d, 64));
        lm = fminf(lm, __shfl_down(lm, d, 64));
        c += __shfl_down(c, d, 64);
      }
      if (lane == 0) {
        s_redf[wv] = cmin;
        s_redf[4 + wv] = cmax;
        s_redf[8 + wv] = mg;
        s_redf[12 + wv] = lm;
        s_redc[wv] = (unsigned)c;
      }
      __syncthreads();
      cmin = fminf(fminf(s_redf[0], s_redf[1]), fminf(s_redf[2], s_redf[3]));
      cmax = fmaxf(fmaxf(s_redf[4], s_redf[5]), fmaxf(s_redf[6], s_redf[7]));
      float mgtT = fminf(fminf(s_redf[8], s_redf[9]), fminf(s_redf[10], s_redf[11]));
      minT = fminf(fminf(s_redf[12], s_redf[13]), fminf(s_redf[14], s_redf[15]));
      unsigned cT = s_redc[0] + s_redc[1] + s_redc[2] + s_redc[3];

      if (cmin == cmax) {  // all candidates identical
        v409 = cmin;
        v410 = (rr + 1u < cT) ? cmin : mgtT;
        break;
      }

      if (cT <= CCAP || level >= 7) {  // O(c^2) exact ranks rr and rr+1
        float* s_cand = (float*)s_wi;
        if (tid == 0) { s_bcf[0] = cmin; s_bcf[1] = mgtT; }  // defaults
#pragma unroll
        for (int i = 0; i < 16; i++)
          if (mask & (1u << i)) {
            unsigned p = atomicAdd(&s_bcu[2], 1u);
            if (p < (unsigned)(CAP + 64) * 2u) s_cand[p] = v[i];
          }
        __syncthreads();
        unsigned cc = s_bcu[2];
        if (cc > (unsigned)(CAP + 64) * 2u) cc = (unsigned)(CAP + 64) * 2u;
        for (unsigned j = tid; j < cc; j += 256) {
          float u = s_cand[j];
          unsigned less = 0, eq = 0;
          for (unsigned kk = 0; kk < cc; kk++) {
            float g = s_cand[kk];
            less += (g < u) ? 1u : 0u;
            eq += (g == u) ? 1u : 0u;
          }
          if (less <= rr && rr < less + eq) s_bcf[0] = u;            // winners identical
          if (less <= rr + 1u && rr + 1u < less + eq) s_bcf[1] = u;  // rank rr+1 if in-set
        }
        __syncthreads();
        v409 = s_bcf[0];
        v410 = s_bcf[1];
        break;
      }

      // ---- refine into target bin (cold path, recompute bins) ----
      float wbin = 1.0f / curbs;
      curlo = curlo + (float)tb * wbin;
      curbs = curbs * (float)NBIN;
      s_hist[tid] = 0u;
      if (tid == 0) s_bcu[2] = 0u;
      __syncthreads();
#pragma unroll
      for (int i = 0; i < 16; i++)
        if (mask & (1u << i)) {
          int b = (int)((v[i] - curlo) * curbs);
          b = b < 0 ? 0 : (b > NBIN - 1 ? NBIN - 1 : b);
          atomicAdd(&s_hist[b], 1u);
        }
      __syncthreads();
      {
        unsigned c1 = s_hist[tid];
        unsigned tot;
        unsigned b2 = block_scan_excl(c1, tid, s_scanA, tot);
        if (b2 <= rr && rr < b2 + c1) {
          s_bcu[0] = (unsigned)tid;
          s_bcu[1] = rr - b2;
        }
      }
      __syncthreads();
      tb = s_bcu[0];
      rr = s_bcu[1];
      unsigned nmask = 0;
#pragma unroll
      for (int i = 0; i < 16; i++)
        if (mask & (1u << i)) {
          int b = (int)((v[i] - curlo) * curbs);
          b = b < 0 ? 0 : (b > NBIN - 1 ? NBIN - 1 : b);
          if ((unsigned)b == tb) nmask |= (1u << i);
          else if ((unsigned)b > tb) mgt_run = fminf(mgt_run, v[i]);
        }
      mask = nmask;
    }

    float thr = 0.5f * v409 + 0.5f * v410;  // frac = 0.5 exactly (jax lerp midpoint)

    // ---- select <= thr: scan for positions ----
    unsigned cnt = 0;
#pragma unroll
    for (int i = 0; i < 16; i++)
      if (v[i] <= thr) cnt++;
    unsigned incl = cnt;
#pragma unroll
    for (int d = 1; d < 64; d <<= 1) {
      unsigned o = __shfl_up(incl, d, 64);
      if (lane >= d) incl += o;
    }
    if (lane == 63) s_scanB[wv] = incl;
    __syncthreads();
    unsigned base = incl - cnt;
#pragma unroll
    for (int w = 0; w < 4; w++)
      if (w < wv) base += s_scanB[w];
    unsigned M = s_scanB[0] + s_scanB[1] + s_scanB[2] + s_scanB[3];

    // ---- chunked gather: entries hold (weight, byte-offset); 16 lanes x f4/row
    floatx4 acc4 = {0.f, 0.f, 0.f, 0.f};
    float psum = 0.f;
    for (unsigned c0 = 0; c0 < M; c0 += CAP) {
      unsigned len = M - c0;
      if (len > CAP) len = CAP;
      unsigned padded = (len + 63u) & ~63u;  // multiple of 64 entries
      __syncthreads();                       // prior readers of s_wi done
      if ((unsigned)tid < padded - len) s_wi[len + tid] = make_float2(0.f, __int_as_float(0));
      unsigned p = base;
#pragma unroll
      for (int i = 0; i < 16; i++)
        if (v[i] <= thr) {
          unsigned rel = p - c0;  // unsigned wrap -> skipped when p < c0
          if (rel < len) {
            float pw = __expf(minT - v[i]);
            s_wi[rel] = make_float2(pw, __int_as_float((tid * 16 + i) << 8));
            psum += pw;  // each selected element contributes in exactly one chunk
          }
          p++;
        }
      __syncthreads();
      for (unsigned t0 = 0; t0 < padded; t0 += 64) {
        unsigned j = t0 + (unsigned)slot2;
        float4 e01 = *reinterpret_cast<const float4*>(&s_wi[j]);        // entries j, j+1
        float4 e23 = *reinterpret_cast<const float4*>(&s_wi[j + 32]);   // entries j+32, j+33
        floatx4 a0 = *reinterpret_cast<const floatx4*>(vpb + __float_as_int(e01.y));
        floatx4 a1 = *reinterpret_cast<const floatx4*>(vpb + __float_as_int(e01.w));
        floatx4 a2 = *reinterpret_cast<const floatx4*>(vpb + __float_as_int(e23.y));
        floatx4 a3 = *reinterpret_cast<const floatx4*>(vpb + __float_as_int(e23.w));
        acc4.x = fmaf(e01.x, a0.x, acc4.x);
        acc4.y = fmaf(e01.x, a0.y, acc4.y);
        acc4.z = fmaf(e01.x, a0.z, acc4.z);
        acc4.w = fmaf(e01.x, a0.w, acc4.w);
        acc4.x = fmaf(e01.z, a1.x, acc4.x);
        acc4.y = fmaf(e01.z, a1.y, acc4.y);
        acc4.z = fmaf(e01.z, a1.z, acc4.z);
        acc4.w = fmaf(e01.z, a1.w, acc4.w);
        acc4.x = fmaf(e23.x, a2.x, acc4.x);
        acc4.y = fmaf(e23.x, a2.y, acc4.y);
        acc4.z = fmaf(e23.x, a2.z, acc4.z);
        acc4.w = fmaf(e23.x, a2.w, acc4.w);
        acc4.x = fmaf(e23.z, a3.x, acc4.x);
        acc4.y = fmaf(e23.z, a3.y, acc4.y);
        acc4.z = fmaf(e23.z, a3.z, acc4.z);
        acc4.w = fmaf(e23.z, a3.w, acc4.w);
      }
    }
    // denominator: reduce per-thread psum (order-fixed -> deterministic)
#pragma unroll
    for (int d = 32; d; d >>= 1) psum += __shfl_down(psum, d, 64);
    if (lane == 0) s_psum[wv] = psum;
    *reinterpret_cast<floatx4*>(&s_out[wv * 4 + (lane >> 4)][(lane & 15) * 4]) = acc4;
    __syncthreads();

    if (tid < 64) {
      float denom = ((s_psum[0] + s_psum[1]) + s_psum[2]) + s_psum[3];
      float invd = 1.0f / denom;
      float totv = 0.f;
#pragma unroll
      for (int g = 0; g < 16; g++) totv += s_out[g][tid];
      float xo = totv * invd;
      float x3 = xo * xo * xo;
      float inner = 0.7978845608028654f * (xo + 0.044715f * x3);
      float g = 0.5f * xo * (1.0f + tanhf(inner));
      int bb = tid >> 5, kk = tid & 31;
      out[((size_t)bb * NSEQ + q) * (NH * VD) + (size_t)h * VD + kk] = g;
    }
    __syncthreads();  // row epilogue complete before next row reuses buffers
  }
}

// ---------------- launch ----------------------------------------------------

extern "C" void kernel_launch(void* const* d_in, const int* in_sizes, int n_in,
                              void* d_out, int out_size, void* d_ws, size_t ws_size,
                              hipStream_t stream) {
  const float* m_dist = (const float*)d_in[0];
  const float* x = (const float*)d_in[1];
  const float* r = (const float*)d_in[2];
  const float* w = (const float*)d_in[3];
  float* out = (float*)d_out;

  float* value = (float*)d_ws;                          // NH*NSEQ*NB*VD floats = 8 MB
  float* scales = value + (size_t)NH * NSEQ * NB * VD;  // + 8 floats

  value_kernel<<<dim3(NSEQ / 8), dim3(256), 0, stream>>>(x, w, r, value, scales);
  attn_kernel<<<dim3(NH * NSEQ / ROWS), dim3(256), 0, stream>>>(m_dist, value, scales, out);
}

// Round 7
// 434.914 us; speedup vs baseline: 3.0367x; 3.0367x over previous
//
#include <hip/hip_runtime.h>
#include <hip/hip_bf16.h>
#include <math.h>

#define NH   8
#define NSEQ 4096
#define NB   2
#define HID  256
#define VD   32
#define RANK 409   // 0-indexed; percentile pos = 0.1*(4096-1) = 409.5 -> lerp(s[409],s[410],0.5)
#define NBIN 256
#define CAP  512   // chunked select buffer (M ~ 410 for this data -> 1 chunk)
#define CCAP 1024  // max candidates handled by O(c^2) rank path
#define ROWS 16    // rows per persistent block; grid = NH*NSEQ/ROWS = 2048 = 8/CU

typedef float floatx4 __attribute__((ext_vector_type(4)));

// exclusive scan over 256 per-thread counts; returns base; total via ref
__device__ __forceinline__ unsigned block_scan_excl(unsigned c, int tid,
                                                    volatile unsigned* s4,
                                                    unsigned& total) {
  const int lane = tid & 63, w = tid >> 6;
  unsigned incl = c;
#pragma unroll
  for (int d = 1; d < 64; d <<= 1) {
    unsigned o = __shfl_up(incl, d, 64);
    if (lane >= d) incl += o;
  }
  __syncthreads();
  if (lane == 63) s4[w] = incl;
  __syncthreads();
  unsigned base = 0;
#pragma unroll
  for (int i = 0; i < 4; i++)
    if (i < w) base += s4[i];
  total = s4[0] + s4[1] + s4[2] + s4[3];
  return base + incl - c;
}

// ---------------- kernel A: value[h][n][b*32+k] = x @ weight; + scales ------

__global__ __launch_bounds__(256) void value_kernel(
    const float* __restrict__ x, const float* __restrict__ w,
    const float* __restrict__ r, float* __restrict__ value,
    float* __restrict__ scales) {
  const int tid = threadIdx.x;

  if (blockIdx.x == 0 && tid < NH) {
    double rv = (double)r[tid];
    const float c0 = (float)(0.25 * 3.141592653589793 * (1.0 - 1e-07));
    float s1 = (float)sin(rv);
    float t = c0 * (1.0f + s1);
    scales[tid] = (float)tan((double)t);
  }

  const int n0 = blockIdx.x * 8;
  __shared__ float sx[NB][8][HID];
#pragma unroll
  for (int i = 0; i < 16; i++) {
    int idx = i * 256 + tid;
    int b = idx >> 11;
    int rem = idx & 2047;
    int nn = rem >> 8;
    int j = rem & 255;
    sx[b][nn][j] = x[((size_t)b * NSEQ + n0 + nn) * HID + j];
  }
  __syncthreads();

  const int h = tid >> 5, k = tid & 31;
  float acc[NB][8];
#pragma unroll
  for (int b = 0; b < NB; b++)
#pragma unroll
    for (int nn = 0; nn < 8; nn++) acc[b][nn] = 0.f;

  const float* wp = w + (size_t)h * HID * VD + k;
  for (int j4 = 0; j4 < HID; j4 += 4) {
    float wv0 = wp[(size_t)(j4 + 0) * VD];
    float wv1 = wp[(size_t)(j4 + 1) * VD];
    float wv2 = wp[(size_t)(j4 + 2) * VD];
    float wv3 = wp[(size_t)(j4 + 3) * VD];
#pragma unroll
    for (int b = 0; b < NB; b++) {
#pragma unroll
      for (int nn = 0; nn < 8; nn++) {
        const float4 xv = *reinterpret_cast<const float4*>(&sx[b][nn][j4]);
        float a = acc[b][nn];
        a = fmaf(xv.x, wv0, a);
        a = fmaf(xv.y, wv1, a);
        a = fmaf(xv.z, wv2, a);
        a = fmaf(xv.w, wv3, a);
        acc[b][nn] = a;
      }
    }
  }
#pragma unroll
  for (int b = 0; b < NB; b++)
#pragma unroll
    for (int nn = 0; nn < 8; nn++)
      value[((size_t)h * NSEQ + n0 + nn) * (NB * VD) + b * VD + k] = acc[b][nn];
}

// ---------------- kernel B: persistent; per row: percentile->softmax->gather

__global__ __launch_bounds__(256, 4) void attn_kernel(
    const float* __restrict__ m_dist, const float* __restrict__ value,
    const float* __restrict__ scales, float* __restrict__ out) {
  const int tid = threadIdx.x;
  const int lane = tid & 63;
  const int wv = tid >> 6;
  // 2048 blocks; blk&7 presumed XCD id -> one head per XCD (value slice L2-resident)
  const int blk = blockIdx.x;
  const int h = blk & 7;
  const int qbase = (blk >> 3) * ROWS;

  __shared__ unsigned s_hist[NBIN];       // 1 KB
  __shared__ float4 s_wi4[(CAP + 64) / 2];  // 4.5 KB select buffer (16B-aligned)
  __shared__ float s_out[16][64];         // 4 KB: [wave*4+slot][col]
  __shared__ unsigned s_scanA[4];
  __shared__ unsigned s_scanB[4];
  __shared__ float s_psum[4];
  __shared__ float s_redf[16];            // cmin[4], cmax[4], mgt[4], lmin[4]
  __shared__ unsigned s_redc[4];
  __shared__ unsigned s_bcu[4];
  __shared__ float s_bcf[2];
  float2* s_wi = reinterpret_cast<float2*>(s_wi4);

  // hoisted per-head constants
  const float scale = scales[h];
  const float binscale = (float)NBIN / scale;  // inf/0-safe: cvt NaN->0, clamped
  const char* vpb = (const char*)(value + (size_t)h * (NSEQ * NB * VD)) + (lane & 15) * 16;
  const int slot2 = ((wv * 4) + (lane >> 4)) * 2;  // gather: entry pair index within 64

  for (int rit = 0; rit < ROWS; ++rit) {
    const int q = qbase + rit;
    const size_t rowbase = ((size_t)(h * NSEQ + q)) * NSEQ;

    // ---- load row (thread owns n = 16*tid + i), scale, local min ----
    float v[16];
    {
      const floatx4* row4 = reinterpret_cast<const floatx4*>(m_dist + rowbase) + (size_t)tid * 4;
#pragma unroll
      for (int a = 0; a < 4; a++) {
        floatx4 t4 = __builtin_nontemporal_load(&row4[a]);
        v[4 * a + 0] = t4.x * scale;
        v[4 * a + 1] = t4.y * scale;
        v[4 * a + 2] = t4.z * scale;
        v[4 * a + 3] = t4.w * scale;
      }
    }
    float lmin = v[0];
#pragma unroll
    for (int i = 1; i < 16; i++) lmin = fminf(lmin, v[i]);

    s_hist[tid] = 0u;  // NBIN == 256
    __syncthreads();

    // ---- level-0 histogram; bins kept in registers (computed ONCE) ----
    int bins[16];
#pragma unroll
    for (int i = 0; i < 16; i++) {
      int b = (int)(v[i] * binscale);
      b = b < 0 ? 0 : (b > NBIN - 1 ? NBIN - 1 : b);
      bins[i] = b;
      atomicAdd(&s_hist[b], 1u);
    }
    __syncthreads();

    // ---- locate bin containing rank RANK (1 bin per thread) ----
    {
      unsigned c1 = s_hist[tid];
      unsigned tot;
      unsigned base = block_scan_excl(c1, tid, s_scanA, tot);
      if (base <= (unsigned)RANK && (unsigned)RANK < base + c1) {
        s_bcu[0] = (unsigned)tid;
        s_bcu[1] = (unsigned)RANK - base;
      }
      if (tid == 0) s_bcu[2] = 0u;
    }
    __syncthreads();
    unsigned tb = s_bcu[0];
    unsigned rr = s_bcu[1];

    // ---- mask of candidates + running min-above-bin ----
    unsigned mask = 0;
    float mgt_run = INFINITY;
#pragma unroll
    for (int i = 0; i < 16; i++) {
      if ((unsigned)bins[i] == tb) mask |= (1u << i);
      else if ((unsigned)bins[i] > tb) mgt_run = fminf(mgt_run, v[i]);
    }

    float curlo = 0.f, curbs = binscale;  // cold-path refine state
    float v409, v410, minT;

    // ---- multi-level rank refinement (hot path exits at level 0) ----
    for (int level = 0;; level++) {
      float cmin = INFINITY, cmax = -INFINITY;
      int c = 0;
#pragma unroll
      for (int i = 0; i < 16; i++)
        if (mask & (1u << i)) {
          cmin = fminf(cmin, v[i]);
          cmax = fmaxf(cmax, v[i]);
          c++;
        }
      float mg = mgt_run, lm = lmin;
#pragma unroll
      for (int d = 32; d; d >>= 1) {
        cmin = fminf(cmin, __shfl_down(cmin, d, 64));
        cmax = fmaxf(cmax, __shfl_down(cmax, d, 64));
        mg = fminf(mg, __shfl_down(mg, d, 64));
        lm = fminf(lm, __shfl_down(lm, d, 64));
        c += __shfl_down(c, d, 64);
      }
      if (lane == 0) {
        s_redf[wv] = cmin;
        s_redf[4 + wv] = cmax;
        s_redf[8 + wv] = mg;
        s_redf[12 + wv] = lm;
        s_redc[wv] = (unsigned)c;
      }
      __syncthreads();
      cmin = fminf(fminf(s_redf[0], s_redf[1]), fminf(s_redf[2], s_redf[3]));
      cmax = fmaxf(fmaxf(s_redf[4], s_redf[5]), fmaxf(s_redf[6], s_redf[7]));
      float mgtT = fminf(fminf(s_redf[8], s_redf[9]), fminf(s_redf[10], s_redf[11]));
      minT = fminf(fminf(s_redf[12], s_redf[13]), fminf(s_redf[14], s_redf[15]));
      unsigned cT = s_redc[0] + s_redc[1] + s_redc[2] + s_redc[3];

      if (cmin == cmax) {  // all candidates identical
        v409 = cmin;
        v410 = (rr + 1u < cT) ? cmin : mgtT;
        break;
      }

      if (cT <= CCAP || level >= 7) {  // O(c^2) exact ranks rr and rr+1
        float* s_cand = (float*)s_wi;
        if (tid == 0) { s_bcf[0] = cmin; s_bcf[1] = mgtT; }  // defaults
#pragma unroll
        for (int i = 0; i < 16; i++)
          if (mask & (1u << i)) {
            unsigned p = atomicAdd(&s_bcu[2], 1u);
            if (p < (unsigned)(CAP + 64) * 2u) s_cand[p] = v[i];
          }
        __syncthreads();
        unsigned cc = s_bcu[2];
        if (cc > (unsigned)(CAP + 64) * 2u) cc = (unsigned)(CAP + 64) * 2u;
        for (unsigned j = tid; j < cc; j += 256) {
          float u = s_cand[j];
          unsigned less = 0, eq = 0;
          for (unsigned kk = 0; kk < cc; kk++) {
            float g = s_cand[kk];
            less += (g < u) ? 1u : 0u;
            eq += (g == u) ? 1u : 0u;
          }
          if (less <= rr && rr < less + eq) s_bcf[0] = u;            // winners identical
          if (less <= rr + 1u && rr + 1u < less + eq) s_bcf[1] = u;  // rank rr+1 if in-set
        }
        __syncthreads();
        v409 = s_bcf[0];
        v410 = s_bcf[1];
        break;
      }

      // ---- refine into target bin (cold path, recompute bins) ----
      float wbin = 1.0f / curbs;
      curlo = curlo + (float)tb * wbin;
      curbs = curbs * (float)NBIN;
      s_hist[tid] = 0u;
      if (tid == 0) s_bcu[2] = 0u;
      __syncthreads();
#pragma unroll
      for (int i = 0; i < 16; i++)
        if (mask & (1u << i)) {
          int b = (int)((v[i] - curlo) * curbs);
          b = b < 0 ? 0 : (b > NBIN - 1 ? NBIN - 1 : b);
          atomicAdd(&s_hist[b], 1u);
        }
      __syncthreads();
      {
        unsigned c1 = s_hist[tid];
        unsigned tot;
        unsigned b2 = block_scan_excl(c1, tid, s_scanA, tot);
        if (b2 <= rr && rr < b2 + c1) {
          s_bcu[0] = (unsigned)tid;
          s_bcu[1] = rr - b2;
        }
      }
      __syncthreads();
      tb = s_bcu[0];
      rr = s_bcu[1];
      unsigned nmask = 0;
#pragma unroll
      for (int i = 0; i < 16; i++)
        if (mask & (1u << i)) {
          int b = (int)((v[i] - curlo) * curbs);
          b = b < 0 ? 0 : (b > NBIN - 1 ? NBIN - 1 : b);
          if ((unsigned)b == tb) nmask |= (1u << i);
          else if ((unsigned)b > tb) mgt_run = fminf(mgt_run, v[i]);
        }
      mask = nmask;
    }

    float thr = 0.5f * v409 + 0.5f * v410;  // frac = 0.5 exactly (jax lerp midpoint)

    // ---- select <= thr: scan for positions ----
    unsigned cnt = 0;
#pragma unroll
    for (int i = 0; i < 16; i++)
      if (v[i] <= thr) cnt++;
    unsigned incl = cnt;
#pragma unroll
    for (int d = 1; d < 64; d <<= 1) {
      unsigned o = __shfl_up(incl, d, 64);
      if (lane >= d) incl += o;
    }
    if (lane == 63) s_scanB[wv] = incl;
    __syncthreads();
    unsigned base = incl - cnt;
#pragma unroll
    for (int w = 0; w < 4; w++)
      if (w < wv) base += s_scanB[w];
    unsigned M = s_scanB[0] + s_scanB[1] + s_scanB[2] + s_scanB[3];

    // ---- chunked gather: entries hold (weight, byte-offset); 16 lanes x f4/row
    floatx4 acc4 = {0.f, 0.f, 0.f, 0.f};
    float psum = 0.f;
    for (unsigned c0 = 0; c0 < M; c0 += CAP) {
      unsigned len = M - c0;
      if (len > CAP) len = CAP;
      unsigned padded = (len + 63u) & ~63u;  // multiple of 64 entries
      __syncthreads();                       // prior readers of s_wi done
      if ((unsigned)tid < padded - len) s_wi[len + tid] = make_float2(0.f, __int_as_float(0));
      unsigned p = base;
#pragma unroll
      for (int i = 0; i < 16; i++)
        if (v[i] <= thr) {
          unsigned rel = p - c0;  // unsigned wrap -> skipped when p < c0
          if (rel < len) {
            float pw = __expf(minT - v[i]);
            s_wi[rel] = make_float2(pw, __int_as_float((tid * 16 + i) << 8));
            psum += pw;  // each selected element contributes in exactly one chunk
          }
          p++;
        }
      __syncthreads();
      for (unsigned t0 = 0; t0 < padded; t0 += 64) {
        unsigned j = t0 + (unsigned)slot2;
        float4 e01 = *reinterpret_cast<const float4*>(&s_wi[j]);        // entries j, j+1
        float4 e23 = *reinterpret_cast<const float4*>(&s_wi[j + 32]);   // entries j+32, j+33
        floatx4 a0 = *reinterpret_cast<const floatx4*>(vpb + __float_as_int(e01.y));
        floatx4 a1 = *reinterpret_cast<const floatx4*>(vpb + __float_as_int(e01.w));
        floatx4 a2 = *reinterpret_cast<const floatx4*>(vpb + __float_as_int(e23.y));
        floatx4 a3 = *reinterpret_cast<const floatx4*>(vpb + __float_as_int(e23.w));
        acc4.x = fmaf(e01.x, a0.x, acc4.x);
        acc4.y = fmaf(e01.x, a0.y, acc4.y);
        acc4.z = fmaf(e01.x, a0.z, acc4.z);
        acc4.w = fmaf(e01.x, a0.w, acc4.w);
        acc4.x = fmaf(e01.z, a1.x, acc4.x);
        acc4.y = fmaf(e01.z, a1.y, acc4.y);
        acc4.z = fmaf(e01.z, a1.z, acc4.z);
        acc4.w = fmaf(e01.z, a1.w, acc4.w);
        acc4.x = fmaf(e23.x, a2.x, acc4.x);
        acc4.y = fmaf(e23.x, a2.y, acc4.y);
        acc4.z = fmaf(e23.x, a2.z, acc4.z);
        acc4.w = fmaf(e23.x, a2.w, acc4.w);
        acc4.x = fmaf(e23.z, a3.x, acc4.x);
        acc4.y = fmaf(e23.z, a3.y, acc4.y);
        acc4.z = fmaf(e23.z, a3.z, acc4.z);
        acc4.w = fmaf(e23.z, a3.w, acc4.w);
      }
    }
    // denominator: reduce per-thread psum (order-fixed -> deterministic)
#pragma unroll
    for (int d = 32; d; d >>= 1) psum += __shfl_down(psum, d, 64);
    if (lane == 0) s_psum[wv] = psum;
    *reinterpret_cast<floatx4*>(&s_out[wv * 4 + (lane >> 4)][(lane & 15) * 4]) = acc4;
    __syncthreads();

    if (tid < 64) {
      float denom = ((s_psum[0] + s_psum[1]) + s_psum[2]) + s_psum[3];
      float invd = 1.0f / denom;
      float totv = 0.f;
#pragma unroll
      for (int g = 0; g < 16; g++) totv += s_out[g][tid];
      float xo = totv * invd;
      float x3 = xo * xo * xo;
      float inner = 0.7978845608028654f * (xo + 0.044715f * x3);
      float g = 0.5f * xo * (1.0f + tanhf(inner));
      int bb = tid >> 5, kk = tid & 31;
      out[((size_t)bb * NSEQ + q) * (NH * VD) + (size_t)h * VD + kk] = g;
    }
    __syncthreads();  // row epilogue complete before next row reuses buffers
  }
}

// ---------------- launch ----------------------------------------------------

extern "C" void kernel_launch(void* const* d_in, const int* in_sizes, int n_in,
                              void* d_out, int out_size, void* d_ws, size_t ws_size,
                              hipStream_t stream) {
  const float* m_dist = (const float*)d_in[0];
  const float* x = (const float*)d_in[1];
  const float* r = (const float*)d_in[2];
  const float* w = (const float*)d_in[3];
  float* out = (float*)d_out;

  float* value = (float*)d_ws;                          // NH*NSEQ*NB*VD floats = 8 MB
  float* scales = value + (size_t)NH * NSEQ * NB * VD;  // + 8 floats

  value_kernel<<<dim3(NSEQ / 8), dim3(256), 0, stream>>>(x, w, r, value, scales);
  attn_kernel<<<dim3(NH * NSEQ / ROWS), dim3(256), 0, stream>>>(m_dist, value, scales, out);
}

// Round 8
// 334.498 us; speedup vs baseline: 3.9484x; 1.3002x over previous
//
#include <hip/hip_runtime.h>
#include <hip/hip_bf16.h>
#include <math.h>

#define NH   8
#define NSEQ 4096
#define NB   2
#define HID  256
#define VD   32
#define RANK 409     // 0-indexed; pos = 0.1*(4096-1) = 409.5 -> lerp(s[409],s[410],0.5)
#define NBIN 256     // candidate-space histogram bins
#define WCAP 1024    // candidate / select buffer entries
#define TG   0.1171875f  // initial threshold fraction (uniform: cnt ~ 480)

typedef float floatx4 __attribute__((ext_vector_type(4)));

// exclusive scan over 256 per-thread counts; returns base; total via ref
__device__ __forceinline__ unsigned block_scan_excl(unsigned c, int tid,
                                                    volatile unsigned* s4,
                                                    unsigned& total) {
  const int lane = tid & 63, w = tid >> 6;
  unsigned incl = c;
#pragma unroll
  for (int d = 1; d < 64; d <<= 1) {
    unsigned o = __shfl_up(incl, d, 64);
    if (lane >= d) incl += o;
  }
  __syncthreads();
  if (lane == 63) s4[w] = incl;
  __syncthreads();
  unsigned base = 0;
#pragma unroll
  for (int i = 0; i < 4; i++)
    if (i < w) base += s4[i];
  total = s4[0] + s4[1] + s4[2] + s4[3];
  return base + incl - c;
}

// block count of v[i] <= t  (cold path helper)
__device__ __forceinline__ int block_cnt_le(const float* v, float t, int lane, int wv,
                                            volatile unsigned* s4) {
  int c = 0;
#pragma unroll
  for (int i = 0; i < 16; i++) c += (v[i] <= t) ? 1 : 0;
#pragma unroll
  for (int d = 32; d; d >>= 1) c += __shfl_down(c, d, 64);
  __syncthreads();
  if (lane == 0) s4[wv] = (unsigned)c;
  __syncthreads();
  return (int)(s4[0] + s4[1] + s4[2] + s4[3]);
}

// ---------------- kernel A: value[h][n][b*32+k] = x @ weight; + scales ------

__global__ __launch_bounds__(256) void value_kernel(
    const float* __restrict__ x, const float* __restrict__ w,
    const float* __restrict__ r, float* __restrict__ value,
    float* __restrict__ scales) {
  const int tid = threadIdx.x;

  if (blockIdx.x == 0 && tid < NH) {
    double rv = (double)r[tid];
    const float c0 = (float)(0.25 * 3.141592653589793 * (1.0 - 1e-07));
    float s1 = (float)sin(rv);
    float t = c0 * (1.0f + s1);
    scales[tid] = (float)tan((double)t);
  }

  const int n0 = blockIdx.x * 8;
  __shared__ float sx[NB][8][HID];
#pragma unroll
  for (int i = 0; i < 16; i++) {
    int idx = i * 256 + tid;
    int b = idx >> 11;
    int rem = idx & 2047;
    int nn = rem >> 8;
    int j = rem & 255;
    sx[b][nn][j] = x[((size_t)b * NSEQ + n0 + nn) * HID + j];
  }
  __syncthreads();

  const int h = tid >> 5, k = tid & 31;
  float acc[NB][8];
#pragma unroll
  for (int b = 0; b < NB; b++)
#pragma unroll
    for (int nn = 0; nn < 8; nn++) acc[b][nn] = 0.f;

  const float* wp = w + (size_t)h * HID * VD + k;
  for (int j4 = 0; j4 < HID; j4 += 4) {
    float wv0 = wp[(size_t)(j4 + 0) * VD];
    float wv1 = wp[(size_t)(j4 + 1) * VD];
    float wv2 = wp[(size_t)(j4 + 2) * VD];
    float wv3 = wp[(size_t)(j4 + 3) * VD];
#pragma unroll
    for (int b = 0; b < NB; b++) {
#pragma unroll
      for (int nn = 0; nn < 8; nn++) {
        const float4 xv = *reinterpret_cast<const float4*>(&sx[b][nn][j4]);
        float a = acc[b][nn];
        a = fmaf(xv.x, wv0, a);
        a = fmaf(xv.y, wv1, a);
        a = fmaf(xv.z, wv2, a);
        a = fmaf(xv.w, wv3, a);
        acc[b][nn] = a;
      }
    }
  }
#pragma unroll
  for (int b = 0; b < NB; b++)
#pragma unroll
    for (int nn = 0; nn < 8; nn++)
      value[((size_t)h * NSEQ + n0 + nn) * (NB * VD) + b * VD + k] = acc[b][nn];
}

// ---------------- kernel B: per (h,q): T-guess compaction -> candidate-space
//                  selection -> weights-in-LDS -> gather ---------------------

__global__ __launch_bounds__(256, 5) void attn_kernel(
    const float* __restrict__ m_dist, const float* __restrict__ value,
    const float* __restrict__ scales, float* __restrict__ out) {
  const int tid = threadIdx.x;
  const int lane = tid & 63;
  const int wv = tid >> 6;
  // 32768 blocks; bid0&7 -> head == XCD (value slice L2-resident per XCD)
  const int bid0 = blockIdx.x;
  const int h = bid0 & 7;
  const int q = bid0 >> 3;

  __shared__ unsigned s_hist[NBIN];        // 1 KB
  __shared__ float4 s_wi4[(WCAP + 64) / 2];  // 8.5 KB (v,off) then (w,off)
  __shared__ float s_small[48];            // in-bin candidates
  __shared__ float s_out[16][64];          // 4 KB
  __shared__ unsigned s_scanA[4];
  __shared__ unsigned s_redc[4];
  __shared__ float s_redf[8];
  __shared__ float s_psum[4];
  __shared__ unsigned s_bcu[4];
  __shared__ float s_bcf[2];
  float2* s_wi = reinterpret_cast<float2*>(s_wi4);

  const float scale = scales[h];
  const size_t rowbase = ((size_t)(h * NSEQ + q)) * NSEQ;
  const char* vpb = (const char*)(value + (size_t)h * (NSEQ * NB * VD)) + (lane & 15) * 16;
  const int slot2 = ((wv * 4) + (lane >> 4)) * 2;

  // ---- phase 1: load row (n = 16*tid + i), scale; lmin; count <= T0 ----
  float v[16];
  {
    const floatx4* row4 = reinterpret_cast<const floatx4*>(m_dist + rowbase) + (size_t)tid * 4;
#pragma unroll
    for (int a = 0; a < 4; a++) {
      floatx4 t4 = __builtin_nontemporal_load(&row4[a]);
      v[4 * a + 0] = t4.x * scale;
      v[4 * a + 1] = t4.y * scale;
      v[4 * a + 2] = t4.z * scale;
      v[4 * a + 3] = t4.w * scale;
    }
  }
  float T = TG * scale;
  float lmin = v[0];
  int cnt = (v[0] <= T) ? 1 : 0;
#pragma unroll
  for (int i = 1; i < 16; i++) {
    lmin = fminf(lmin, v[i]);
    cnt += (v[i] <= T) ? 1 : 0;
  }
  s_hist[tid] = 0u;
  if (tid < 4) s_bcu[tid] = 0u;

  // fused block reduce: cnt total + global min
  {
    int c = cnt;
    float lm = lmin;
#pragma unroll
    for (int d = 32; d; d >>= 1) {
      c += __shfl_down(c, d, 64);
      lm = fminf(lm, __shfl_down(lm, d, 64));
    }
    if (lane == 0) { s_redc[wv] = (unsigned)c; s_redf[wv] = lm; }
  }
  __syncthreads();
  int cntT = (int)(s_redc[0] + s_redc[1] + s_redc[2] + s_redc[3]);
  const float minT = fminf(fminf(s_redf[0], s_redf[1]), fminf(s_redf[2], s_redf[3]));

  bool hot = (cntT >= RANK + 2) && (cntT <= WCAP);

  float psum = 0.f;
  floatx4 acc4 = {0.f, 0.f, 0.f, 0.f};

  if (!hot) {
    // ---- cold: bisect T so cnt in [411, WCAP]; exact tie path if impossible ----
    float lo = -1.0f, hi = scale;
    if (!(hi > lo)) hi = 1.0f;  // degenerate scale guard
    for (int it = 0; it < 64; it++) {
      float mid = 0.5f * (lo + hi);
      if (!(mid > lo && mid < hi)) break;
      int c = block_cnt_le(v, mid, lane, wv, s_redc);
      if (c < RANK + 2) lo = mid;
      else if (c > WCAP) hi = mid;
      else { T = mid; cntT = c; hot = true; break; }
    }
    if (!hot) {
      // ties spanning ranks: derive thr exactly via reduces
      int c_lo = block_cnt_le(v, lo, lane, wv, s_redc);
      float mn = INFINITY, mx = -INFINITY;
#pragma unroll
      for (int i = 0; i < 16; i++) {
        if (v[i] > lo) mn = fminf(mn, v[i]);
        if (v[i] <= lo) mx = fmaxf(mx, v[i]);
      }
#pragma unroll
      for (int d = 32; d; d >>= 1) {
        mn = fminf(mn, __shfl_down(mn, d, 64));
        mx = fmaxf(mx, __shfl_down(mx, d, 64));
      }
      __syncthreads();
      if (lane == 0) { s_redf[wv] = mn; s_redf[4 + wv] = mx; }
      __syncthreads();
      float vstar = fminf(fminf(s_redf[0], s_redf[1]), fminf(s_redf[2], s_redf[3]));
      float vbelow = fmaxf(fmaxf(s_redf[4], s_redf[5]), fmaxf(s_redf[6], s_redf[7]));
      float s409 = (c_lo == RANK + 1) ? vbelow : vstar;
      float thr = 0.5f * s409 + 0.5f * vstar;

      // chunked select+gather straight from registers (r5 machinery)
      unsigned csel = 0;
#pragma unroll
      for (int i = 0; i < 16; i++)
        if (v[i] <= thr) csel++;
      unsigned M;
      unsigned base = block_scan_excl(csel, tid, s_scanA, M);
      for (unsigned c0 = 0; c0 < M; c0 += WCAP) {
        unsigned len = M - c0;
        if (len > WCAP) len = WCAP;
        unsigned padded = (len + 63u) & ~63u;
        __syncthreads();
        if ((unsigned)tid < padded - len) s_wi[len + tid] = make_float2(0.f, __int_as_float(0));
        unsigned p = base;
#pragma unroll
        for (int i = 0; i < 16; i++)
          if (v[i] <= thr) {
            unsigned rel = p - c0;
            if (rel < len) {
              float pw = __expf(minT - v[i]);
              s_wi[rel] = make_float2(pw, __int_as_float((tid * 16 + i) << 8));
              psum += pw;
            }
            p++;
          }
        __syncthreads();
        for (unsigned t0 = 0; t0 < padded; t0 += 64) {
          unsigned j = t0 + (unsigned)slot2;
          float4 e01 = *reinterpret_cast<const float4*>(&s_wi[j]);
          float4 e23 = *reinterpret_cast<const float4*>(&s_wi[j + 32]);
          floatx4 a0 = *reinterpret_cast<const floatx4*>(vpb + __float_as_int(e01.y));
          floatx4 a1 = *reinterpret_cast<const floatx4*>(vpb + __float_as_int(e01.w));
          floatx4 a2 = *reinterpret_cast<const floatx4*>(vpb + __float_as_int(e23.y));
          floatx4 a3 = *reinterpret_cast<const floatx4*>(vpb + __float_as_int(e23.w));
          acc4.x = fmaf(e01.x, a0.x, acc4.x);
          acc4.y = fmaf(e01.x, a0.y, acc4.y);
          acc4.z = fmaf(e01.x, a0.z, acc4.z);
          acc4.w = fmaf(e01.x, a0.w, acc4.w);
          acc4.x = fmaf(e01.z, a1.x, acc4.x);
          acc4.y = fmaf(e01.z, a1.y, acc4.y);
          acc4.z = fmaf(e01.z, a1.z, acc4.z);
          acc4.w = fmaf(e01.z, a1.w, acc4.w);
          acc4.x = fmaf(e23.x, a2.x, acc4.x);
          acc4.y = fmaf(e23.x, a2.y, acc4.y);
          acc4.z = fmaf(e23.x, a2.z, acc4.z);
          acc4.w = fmaf(e23.x, a2.w, acc4.w);
          acc4.x = fmaf(e23.z, a3.x, acc4.x);
          acc4.y = fmaf(e23.z, a3.y, acc4.y);
          acc4.z = fmaf(e23.z, a3.z, acc4.z);
          acc4.w = fmaf(e23.z, a3.w, acc4.w);
        }
      }
    }
  }

  if (hot) {
    // ---- compact candidates (v, byteoff) to LDS; v[] dead afterwards ----
    unsigned csel = 0;
#pragma unroll
    for (int i = 0; i < 16; i++)
      if (v[i] <= T) csel++;
    unsigned M0;
    unsigned base = block_scan_excl(csel, tid, s_scanA, M0);
    {
      unsigned p = base;
#pragma unroll
      for (int i = 0; i < 16; i++)
        if (v[i] <= T) {
          s_wi[p] = make_float2(v[i], __int_as_float((tid * 16 + i) << 8));
          p++;
        }
    }
    __syncthreads();

    // ---- candidate-space histogram (256 bins over [0, T]) ----
    const float binscale = (float)NBIN / T;
    for (unsigned e = tid; e < M0; e += 256) {
      int b = (int)(s_wi[e].x * binscale);
      b = b < 0 ? 0 : (b > NBIN - 1 ? NBIN - 1 : b);
      atomicAdd(&s_hist[b], 1u);
    }
    __syncthreads();

    // ---- locate bin of rank RANK ----
    {
      unsigned c1 = s_hist[tid];
      unsigned tot;
      unsigned b2 = block_scan_excl(c1, tid, s_scanA, tot);
      if (b2 <= (unsigned)RANK && (unsigned)RANK < b2 + c1) {
        s_bcu[0] = (unsigned)tid;
        s_bcu[1] = b2;  // candidates in bins < tb
      }
    }
    __syncthreads();
    const unsigned tb = s_bcu[0];
    const unsigned base_tb = s_bcu[1];

    // ---- collect in-bin candidates + min-above-bin ----
    float mgt = INFINITY;
    for (unsigned e = tid; e < M0; e += 256) {
      float u = s_wi[e].x;
      int b = (int)(u * binscale);
      b = b < 0 ? 0 : (b > NBIN - 1 ? NBIN - 1 : b);
      if ((unsigned)b == tb) {
        unsigned p = atomicAdd(&s_bcu[2], 1u);
        if (p < 48u) s_small[p] = u;
      } else if ((unsigned)b > tb) {
        mgt = fminf(mgt, u);
      }
    }
#pragma unroll
    for (int d = 32; d; d >>= 1) mgt = fminf(mgt, __shfl_down(mgt, d, 64));
    __syncthreads();
    if (lane == 0) s_redf[wv] = mgt;
    __syncthreads();
    const float mgtT = fminf(fminf(s_redf[0], s_redf[1]), fminf(s_redf[2], s_redf[3]));
    if (tid == 0) { s_bcf[0] = mgtT; s_bcf[1] = mgtT; }  // defaults (rank410 above bin)
    __syncthreads();

    // ---- exact ranks 409/410 within bin ----
    const unsigned cbin = s_bcu[2];
    if (cbin <= 48u) {
      if ((unsigned)tid < cbin) {
        float u = s_small[tid];
        unsigned less = 0, eq = 0;
        for (unsigned k = 0; k < cbin; k++) {
          float g = s_small[k];
          less += (g < u) ? 1u : 0u;
          eq += (g == u) ? 1u : 0u;
        }
        unsigned gl = base_tb + less;
        if (gl <= (unsigned)RANK && (unsigned)RANK < gl + eq) s_bcf[0] = u;
        if (gl <= (unsigned)(RANK + 1) && (unsigned)(RANK + 1) < gl + eq) s_bcf[1] = u;
      }
    } else {
      // pathological clustering: O(c*M0) general path (never taken for this data)
      for (unsigned e = tid; e < M0; e += 256) {
        float u = s_wi[e].x;
        int b = (int)(u * binscale);
        b = b < 0 ? 0 : (b > NBIN - 1 ? NBIN - 1 : b);
        if ((unsigned)b == tb) {
          unsigned less = 0, eq = 0;
          for (unsigned k = 0; k < M0; k++) {
            float g = s_wi[k].x;
            less += (g < u) ? 1u : 0u;
            eq += (g == u) ? 1u : 0u;
          }
          if (less <= (unsigned)RANK && (unsigned)RANK < less + eq) s_bcf[0] = u;
          if (less <= (unsigned)(RANK + 1) && (unsigned)(RANK + 1) < less + eq) s_bcf[1] = u;
        }
      }
    }
    __syncthreads();
    const float v409 = s_bcf[0];
    const float v410 = s_bcf[1];
    const float thr = 0.5f * v409 + 0.5f * v410;

    // ---- weight pass over entries (fixed order -> deterministic psum) ----
    const unsigned padded = (M0 + 63u) & ~63u;
    for (unsigned e = tid; e < M0; e += 256) {
      float2 t = s_wi[e];
      float w = (t.x <= thr) ? __expf(minT - t.x) : 0.f;
      psum += w;
      s_wi[e] = make_float2(w, t.y);
    }
    if ((unsigned)tid < padded - M0) s_wi[M0 + tid] = make_float2(0.f, __int_as_float(0));
    __syncthreads();

    // ---- gather: 16 lanes x float4 per entry row, paired LDS reads ----
    for (unsigned t0 = 0; t0 < padded; t0 += 64) {
      unsigned j = t0 + (unsigned)slot2;
      float4 e01 = *reinterpret_cast<const float4*>(&s_wi[j]);
      float4 e23 = *reinterpret_cast<const float4*>(&s_wi[j + 32]);
      floatx4 a0 = *reinterpret_cast<const floatx4*>(vpb + __float_as_int(e01.y));
      floatx4 a1 = *reinterpret_cast<const floatx4*>(vpb + __float_as_int(e01.w));
      floatx4 a2 = *reinterpret_cast<const floatx4*>(vpb + __float_as_int(e23.y));
      floatx4 a3 = *reinterpret_cast<const floatx4*>(vpb + __float_as_int(e23.w));
      acc4.x = fmaf(e01.x, a0.x, acc4.x);
      acc4.y = fmaf(e01.x, a0.y, acc4.y);
      acc4.z = fmaf(e01.x, a0.z, acc4.z);
      acc4.w = fmaf(e01.x, a0.w, acc4.w);
      acc4.x = fmaf(e01.z, a1.x, acc4.x);
      acc4.y = fmaf(e01.z, a1.y, acc4.y);
      acc4.z = fmaf(e01.z, a1.z, acc4.z);
      acc4.w = fmaf(e01.z, a1.w, acc4.w);
      acc4.x = fmaf(e23.x, a2.x, acc4.x);
      acc4.y = fmaf(e23.x, a2.y, acc4.y);
      acc4.z = fmaf(e23.x, a2.z, acc4.z);
      acc4.w = fmaf(e23.x, a2.w, acc4.w);
      acc4.x = fmaf(e23.z, a3.x, acc4.x);
      acc4.y = fmaf(e23.z, a3.y, acc4.y);
      acc4.z = fmaf(e23.z, a3.z, acc4.z);
      acc4.w = fmaf(e23.z, a3.w, acc4.w);
    }
  }

  // ---- common epilogue: denominator, combine, gelu, store ----
#pragma unroll
  for (int d = 32; d; d >>= 1) psum += __shfl_down(psum, d, 64);
  if (lane == 0) s_psum[wv] = psum;
  *reinterpret_cast<floatx4*>(&s_out[wv * 4 + (lane >> 4)][(lane & 15) * 4]) = acc4;
  __syncthreads();

  if (tid < 64) {
    float denom = ((s_psum[0] + s_psum[1]) + s_psum[2]) + s_psum[3];
    float invd = 1.0f / denom;
    float totv = 0.f;
#pragma unroll
    for (int g = 0; g < 16; g++) totv += s_out[g][tid];
    float xo = totv * invd;
    float x3 = xo * xo * xo;
    float inner = 0.7978845608028654f * (xo + 0.044715f * x3);
    float g = 0.5f * xo * (1.0f + tanhf(inner));
    int bb = tid >> 5, kk = tid & 31;
    out[((size_t)bb * NSEQ + q) * (NH * VD) + (size_t)h * VD + kk] = g;
  }
}

// ---------------- launch ----------------------------------------------------

extern "C" void kernel_launch(void* const* d_in, const int* in_sizes, int n_in,
                              void* d_out, int out_size, void* d_ws, size_t ws_size,
                              hipStream_t stream) {
  const float* m_dist = (const float*)d_in[0];
  const float* x = (const float*)d_in[1];
  const float* r = (const float*)d_in[2];
  const float* w = (const float*)d_in[3];
  float* out = (float*)d_out;

  float* value = (float*)d_ws;                          // NH*NSEQ*NB*VD floats = 8 MB
  float* scales = value + (size_t)NH * NSEQ * NB * VD;  // + 8 floats

  value_kernel<<<dim3(NSEQ / 8), dim3(256), 0, stream>>>(x, w, r, value, scales);
  attn_kernel<<<dim3(NH * NSEQ), dim3(256), 0, stream>>>(m_dist, value, scales, out);
}